// Round 1
// baseline (654.996 us; speedup 1.0000x reference)
//
#include <hip/hip_runtime.h>

typedef _Float16 h8 __attribute__((ext_vector_type(8)));
typedef _Float16 h4 __attribute__((ext_vector_type(4)));
typedef float    f4 __attribute__((ext_vector_type(4)));

#define TT 1024
#define FF 64
#define HH 128
#define NTH 512

// XOR swizzle: row stride in h_s is 256B (128 fp16) -> lanes 0..15 reading rows 0..15 at the
// same k would all hit bank 0. XOR byte^=(row&7)<<4  == element^=(row&7)<<3. Bijective per row.
#define HIDX(r,k) ((((r)*128 + (k))) ^ (((r)&7)<<3))
#define XIDX(r,k) ((((r)*64  + (k))) ^ (((r)&7)<<3))

__device__ __forceinline__ float tanh_fast(float v) {
  // tanh(v) = 1 - 2/(e^{2v}+1);  e^{2v} = 2^{v*2/ln2}
  float e = __builtin_amdgcn_exp2f(v * 2.8853900817779268f);
  return 1.0f - 2.0f * __builtin_amdgcn_rcpf(e + 1.0f);
}

__device__ __forceinline__ h8 ld_frag(const _Float16* b, int ilo, int ihi) {
  h4 lo = *(const h4*)(b + ilo);
  h4 hi = *(const h4*)(b + ihi);
  return __builtin_shufflevector(lo, hi, 0, 1, 2, 3, 4, 5, 6, 7);
}

// One persistent block per 2 batch rows. 512 threads = 8 waves; wave w owns gate-columns
// j in [w*16, w*16+16) of EACH of the 4 gates (4 N-tiles of 16), so the elementwise cell
// update is wave-local. Weights held in VGPRs as fp16 MFMA fragments for the whole run.
__global__ __launch_bounds__(NTH, 2) void lstm_persist(
    const float* __restrict__ X, const float* __restrict__ W,
    const float* __restrict__ U, const float* __restrict__ bias,
    const float* __restrict__ Wfc, const float* __restrict__ bfcp,
    float* __restrict__ out)
{
  const int tid  = threadIdx.x;
  const int wv   = tid >> 6;
  const int ln   = tid & 63;
  const int l15  = ln & 15;
  const int lg   = ln >> 4;
  const int row0 = blockIdx.x * 2;
  const int ncol = wv * 16 + l15;   // hidden-unit column j in [0,128)

  __shared__ __align__(16) _Float16 h_s[2][16 * 128];
  __shared__ __align__(16) _Float16 x_s[2][16 * 64];
  __shared__ float red[8][2];

  // ---- persistent weight fragments (fp16 in VGPRs) ----
  // B-frag layout: lane -> col n = l&15 (within tile); k = 32*f + 16*(e>>2) + 4*(l>>4) + (e&3).
  // A uses the SAME k-mapping, so any k-permutation error cancels (k is the reduction axis).
  h8 uf[4][4], wf[4][2];
  float bb[4];
#pragma unroll
  for (int g = 0; g < 4; ++g) {
    const int n = g * 128 + ncol;
#pragma unroll
    for (int f = 0; f < 4; ++f) {
      h8 v;
#pragma unroll
      for (int e = 0; e < 8; ++e) {
        const int k = 32 * f + 16 * (e >> 2) + 4 * lg + (e & 3);
        v[e] = (_Float16)U[k * 512 + n];
      }
      uf[g][f] = v;
    }
#pragma unroll
    for (int f = 0; f < 2; ++f) {
      h8 v;
#pragma unroll
      for (int e = 0; e < 8; ++e) {
        const int k = 32 * f + 16 * (e >> 2) + 4 * lg + (e & 3);
        v[e] = (_Float16)W[k * 512 + n];
      }
      wf[g][f] = v;
    }
    bb[g] = bias[n];
  }
  const float wfc = Wfc[ncol];

  // per-thread LDS fragment-read offsets (elements)
  int hlo[4], hhi[4];
#pragma unroll
  for (int f = 0; f < 4; ++f) {
    hlo[f] = HIDX(l15, 32 * f + 4 * lg);
    hhi[f] = HIDX(l15, 32 * f + 16 + 4 * lg);
  }
  int xlo[2], xhi[2];
#pragma unroll
  for (int f = 0; f < 2; ++f) {
    xlo[f] = XIDX(l15, 32 * f + 4 * lg);
    xhi[f] = XIDX(l15, 32 * f + 16 + 4 * lg);
  }

  // zero LDS (rows 2..15 stay zero forever -> pad rows of the M=16 MFMA tile)
  {
    _Float16* p = &h_s[0][0];
    for (int i = tid; i < 2 * 16 * 128; i += NTH) p[i] = (_Float16)0.0f;
    _Float16* q = &x_s[0][0];
    for (int i = tid; i < 2 * 16 * 64; i += NTH) q[i] = (_Float16)0.0f;
  }
  __syncthreads();

  // x prefetch (depth 2, parity-rotated regs; threads 0..127 move 2 rows x 64 f32)
  const int xrow = tid >> 6;   // valid only for tid<128
  const int xcol = tid & 63;
  int xbase = 0;
  float px0 = 0.f, px1 = 0.f;
  if (tid < 128) {
    xbase = (row0 + xrow) * (TT * FF) + xcol;
    x_s[0][XIDX(xrow, xcol)] = (_Float16)X[xbase];
    px0 = X[xbase + 1 * FF];
    px1 = X[xbase + 2 * FF];
  }
  float c0 = 0.f, c1 = 0.f;
  __syncthreads();

#define STEP(Tt, CUR, NXT, PX) {                                                   \
    f4 acc[4];                                                                     \
    _Pragma("unroll")                                                              \
    for (int g = 0; g < 4; ++g) { f4 a0 = {bb[g], bb[g], bb[g], bb[g]}; acc[g] = a0; } \
    _Pragma("unroll")                                                              \
    for (int f = 0; f < 2; ++f) {                                                  \
      h8 a = ld_frag(&x_s[CUR][0], xlo[f], xhi[f]);                                \
      _Pragma("unroll")                                                            \
      for (int g = 0; g < 4; ++g)                                                  \
        acc[g] = __builtin_amdgcn_mfma_f32_16x16x32_f16(a, wf[g][f], acc[g], 0, 0, 0); \
    }                                                                              \
    _Pragma("unroll")                                                              \
    for (int f = 0; f < 4; ++f) {                                                  \
      h8 a = ld_frag(&h_s[CUR][0], hlo[f], hhi[f]);                                \
      _Pragma("unroll")                                                            \
      for (int g = 0; g < 4; ++g)                                                  \
        acc[g] = __builtin_amdgcn_mfma_f32_16x16x32_f16(a, uf[g][f], acc[g], 0, 0, 0); \
    }                                                                              \
    if (lg == 0) {                                                                 \
      _Pragma("unroll")                                                            \
      for (int r = 0; r < 2; ++r) {                                                \
        float zi = acc[0][r], zf = acc[1][r], zg = acc[2][r], zo = acc[3][r];      \
        float gi = tanh_fast(zi), gf = tanh_fast(zf);                              \
        float gg = tanh_fast(zg), go = tanh_fast(zo);                              \
        float cc = r ? c1 : c0;                                                    \
        cc = gf * cc + gi * gg;                                                    \
        if (r) c1 = cc; else c0 = cc;                                              \
        float hv = go * tanh_fast(cc);                                             \
        h_s[NXT][HIDX(r, ncol)] = (_Float16)hv;                                    \
      }                                                                            \
    }                                                                              \
    if (tid < 128) {                                                               \
      x_s[NXT][XIDX(xrow, xcol)] = (_Float16)(PX);                                 \
      PX = X[xbase + min(Tt + 3, TT - 1) * FF];                                    \
    }                                                                              \
    __syncthreads();                                                               \
  }

  for (int t = 0; t < TT; t += 2) {
    STEP(t,     0, 1, px0)
    STEP(t + 1, 1, 0, px1)
  }
#undef STEP

  // ---- epilogue: y[r] = h_last[r,:] @ Wfc + bfc ----
  float hw0 = (float)h_s[0][HIDX(0, ncol)];
  float hw1 = (float)h_s[0][HIDX(1, ncol)];
  float p0 = hw0 * wfc;
  float p1 = hw1 * wfc;
#pragma unroll
  for (int m = 1; m < 16; m <<= 1) {
    p0 += __shfl_xor(p0, m, 16);
    p1 += __shfl_xor(p1, m, 16);
  }
  if (ln == 0) { red[wv][0] = p0; red[wv][1] = p1; }
  __syncthreads();
  if (tid < 2) {
    float y = bfcp[0];
#pragma unroll
    for (int w2 = 0; w2 < 8; ++w2) y += red[w2][tid];
    out[row0 + tid] = y;
  }
}

extern "C" void kernel_launch(void* const* d_in, const int* in_sizes, int n_in,
                              void* d_out, int out_size, void* d_ws, size_t ws_size,
                              hipStream_t stream) {
  const float* x   = (const float*)d_in[0];
  const float* W   = (const float*)d_in[1];
  const float* U   = (const float*)d_in[2];
  const float* b   = (const float*)d_in[3];
  const float* Wfc = (const float*)d_in[4];
  const float* bfc = (const float*)d_in[5];
  float* out = (float*)d_out;
  hipLaunchKernelGGL(lstm_persist, dim3(256), dim3(NTH), 0, stream,
                     x, W, U, b, Wfc, bfc, out);
}

// Round 2
// 643.668 us; speedup vs baseline: 1.0176x; 1.0176x over previous
//
#include <hip/hip_runtime.h>

typedef _Float16 h8 __attribute__((ext_vector_type(8)));
typedef float    f4 __attribute__((ext_vector_type(4)));

#define TT 1024
#define FF 64
#define NTH 512
#define K2 2.8853900817779268f   // 2/ln2

// swizzle on fp16 element index: byte ^= (row&7)<<4  ==  elem ^= (row&7)<<3
#define HSWZ(r, e) ((e) ^ (((r) & 7) << 3))

__device__ __forceinline__ float tanh_e(float z, float bc) {
  // tanh(z + b) with bc = b*K2 pre-scaled: e = 2^(z*K2 + bc); t = 1 - 2/(e+1)
  float e = __builtin_amdgcn_exp2f(__builtin_fmaf(z, K2, bc));
  return __builtin_fmaf(-2.0f, __builtin_amdgcn_rcpf(e + 1.0f), 1.0f);
}

#define MFMA __builtin_amdgcn_mfma_f32_16x16x32_f16

// One persistent block per 2 batch rows; 8 waves, wave wv owns hidden cols
// [wv*16, wv*16+16) of each of the 4 gates. Weights in VGPRs as fp16 fragments.
// Fragment k-map within a 32-wide k-tile: k = 8*lg + e  -> one ds_read_b128/frag.
__global__ __launch_bounds__(NTH, 2) void lstm_persist(
    const float* __restrict__ X, const float* __restrict__ W,
    const float* __restrict__ U, const float* __restrict__ bias,
    const float* __restrict__ Wfc, const float* __restrict__ bfcp,
    float* __restrict__ out)
{
  const int tid = threadIdx.x;
  const int wv  = tid >> 6, ln = tid & 63;
  const int l15 = ln & 15, lg = ln >> 4;
  const int row0 = blockIdx.x * 2;
  const int ncol = wv * 16 + l15;

  __shared__ __align__(16) _Float16 h_s[2][16 * 128];
  __shared__ __align__(16) _Float16 x_s[2][16 * 64];
  __shared__ float red[8][2];

  // ---- persistent weight fragments; same k-permutation as A-side reads ----
  h8 uf[4][4], wf4[4][2];
  float bbc[4];
#pragma unroll
  for (int g = 0; g < 4; ++g) {
    const int n = g * 128 + ncol;
#pragma unroll
    for (int f = 0; f < 4; ++f) {
      h8 v;
#pragma unroll
      for (int e = 0; e < 8; ++e) v[e] = (_Float16)U[(32 * f + 8 * lg + e) * 512 + n];
      uf[g][f] = v;
    }
#pragma unroll
    for (int f = 0; f < 2; ++f) {
      h8 v;
#pragma unroll
      for (int e = 0; e < 8; ++e) v[e] = (_Float16)W[(32 * f + 8 * lg + e) * 512 + n];
      wf4[g][f] = v;
    }
    bbc[g] = bias[n] * K2;
  }
  const float wfc = Wfc[ncol];

  // per-thread contiguous 16B fragment offsets (element units)
  int hofs[4], xofs[2];
#pragma unroll
  for (int f = 0; f < 4; ++f) hofs[f] = HSWZ(l15, l15 * 128 + 32 * f + 8 * lg);
#pragma unroll
  for (int f = 0; f < 2; ++f) xofs[f] = HSWZ(l15, l15 * 64 + 32 * f + 8 * lg);

  // zero LDS (rows 2..15 remain zero forever -> pad rows of the M=16 tile)
  {
    _Float16* p = &h_s[0][0];
    for (int i = tid; i < 2 * 16 * 128; i += NTH) p[i] = (_Float16)0.0f;
    _Float16* q = &x_s[0][0];
    for (int i = tid; i < 2 * 16 * 64; i += NTH) q[i] = (_Float16)0.0f;
  }
  __syncthreads();

  // x prefetch (depth 2, parity-rotated regs; threads 0..127 move 2 rows x 64 f32)
  const int xrow = tid >> 6;
  const int xcol = tid & 63;
  int xbase = 0;
  float px0 = 0.f, px1 = 0.f;
  if (tid < 128) {
    xbase = (row0 + xrow) * (TT * FF) + xcol;
    x_s[0][HSWZ(xrow, xrow * 64 + xcol)] = (_Float16)X[xbase];
    px0 = X[xbase + 1 * FF];
    px1 = X[xbase + 2 * FF];
  }
  float c0 = 0.f, c1 = 0.f;
  const f4 zq = {0.f, 0.f, 0.f, 0.f};   // persistent zero C-operand (loop-invariant)
  __syncthreads();

#define STEP(Tt, CUR, NXT, PX) {                                                    \
    const _Float16* hb = &h_s[CUR][0];                                              \
    const _Float16* xb = &x_s[CUR][0];                                              \
    h8 xa0 = *(const h8*)(xb + xofs[0]);                                            \
    h8 xa1 = *(const h8*)(xb + xofs[1]);                                            \
    h8 ha0 = *(const h8*)(hb + hofs[0]);                                            \
    h8 ha1 = *(const h8*)(hb + hofs[1]);                                            \
    h8 ha2 = *(const h8*)(hb + hofs[2]);                                            \
    h8 ha3 = *(const h8*)(hb + hofs[3]);                                            \
    f4 acc0 = MFMA(xa0, wf4[0][0], zq, 0, 0, 0);                                    \
    f4 acc1 = MFMA(xa0, wf4[1][0], zq, 0, 0, 0);                                    \
    f4 acc2 = MFMA(xa0, wf4[2][0], zq, 0, 0, 0);                                    \
    f4 acc3 = MFMA(xa0, wf4[3][0], zq, 0, 0, 0);                                    \
    acc0 = MFMA(xa1, wf4[0][1], acc0, 0, 0, 0);                                     \
    acc1 = MFMA(xa1, wf4[1][1], acc1, 0, 0, 0);                                     \
    acc2 = MFMA(xa1, wf4[2][1], acc2, 0, 0, 0);                                     \
    acc3 = MFMA(xa1, wf4[3][1], acc3, 0, 0, 0);                                     \
    acc0 = MFMA(ha0, uf[0][0], acc0, 0, 0, 0);                                      \
    acc1 = MFMA(ha0, uf[1][0], acc1, 0, 0, 0);                                      \
    acc2 = MFMA(ha0, uf[2][0], acc2, 0, 0, 0);                                      \
    acc3 = MFMA(ha0, uf[3][0], acc3, 0, 0, 0);                                      \
    acc0 = MFMA(ha1, uf[0][1], acc0, 0, 0, 0);                                      \
    acc1 = MFMA(ha1, uf[1][1], acc1, 0, 0, 0);                                      \
    acc2 = MFMA(ha1, uf[2][1], acc2, 0, 0, 0);                                      \
    acc3 = MFMA(ha1, uf[3][1], acc3, 0, 0, 0);                                      \
    acc0 = MFMA(ha2, uf[0][2], acc0, 0, 0, 0);                                      \
    acc1 = MFMA(ha2, uf[1][2], acc1, 0, 0, 0);                                      \
    acc2 = MFMA(ha2, uf[2][2], acc2, 0, 0, 0);                                      \
    acc3 = MFMA(ha2, uf[3][2], acc3, 0, 0, 0);                                      \
    acc0 = MFMA(ha3, uf[0][3], acc0, 0, 0, 0);                                      \
    acc1 = MFMA(ha3, uf[1][3], acc1, 0, 0, 0);                                      \
    acc2 = MFMA(ha3, uf[2][3], acc2, 0, 0, 0);                                      \
    acc3 = MFMA(ha3, uf[3][3], acc3, 0, 0, 0);                                      \
    if (lg == 0) {                                                                  \
      _Pragma("unroll")                                                             \
      for (int r = 0; r < 2; ++r) {                                                 \
        float ti = tanh_e(acc0[r], bbc[0]);                                         \
        float tf = tanh_e(acc1[r], bbc[1]);                                         \
        float tc = tanh_e(acc2[r], bbc[2]);                                         \
        float to = tanh_e(acc3[r], bbc[3]);                                         \
        float cc = r ? c1 : c0;                                                     \
        cc = __builtin_fmaf(tf, cc, ti * tc);                                       \
        if (r) c1 = cc; else c0 = cc;                                               \
        float hv = to * tanh_e(cc, 0.0f);                                           \
        h_s[NXT][HSWZ(r, r * 128 + ncol)] = (_Float16)hv;                           \
      }                                                                             \
    }                                                                               \
    if (tid < 128) {                                                                \
      x_s[NXT][HSWZ(xrow, xrow * 64 + xcol)] = (_Float16)(PX);                      \
      PX = X[xbase + min(Tt + 3, TT - 1) * FF];                                     \
    }                                                                               \
    __syncthreads();                                                                \
  }

#pragma unroll 1
  for (int t = 0; t < TT; t += 2) {
    STEP(t,     0, 1, px0)
    STEP(t + 1, 1, 0, px1)
  }
#undef STEP

  // ---- epilogue: y[r] = h_last[r,:] @ Wfc + bfc  (h_last in h_s[0]) ----
  float hw0 = (float)h_s[0][HSWZ(0, 0 * 128 + ncol)];
  float hw1 = (float)h_s[0][HSWZ(1, 1 * 128 + ncol)];
  float p0 = hw0 * wfc;
  float p1 = hw1 * wfc;
#pragma unroll
  for (int m = 1; m < 16; m <<= 1) {
    p0 += __shfl_xor(p0, m, 16);
    p1 += __shfl_xor(p1, m, 16);
  }
  if (ln == 0) { red[wv][0] = p0; red[wv][1] = p1; }
  __syncthreads();
  if (tid < 2) {
    float y = bfcp[0];
#pragma unroll
    for (int w2 = 0; w2 < 8; ++w2) y += red[w2][tid];
    out[row0 + tid] = y;
  }
}

extern "C" void kernel_launch(void* const* d_in, const int* in_sizes, int n_in,
                              void* d_out, int out_size, void* d_ws, size_t ws_size,
                              hipStream_t stream) {
  const float* x   = (const float*)d_in[0];
  const float* W   = (const float*)d_in[1];
  const float* U   = (const float*)d_in[2];
  const float* b   = (const float*)d_in[3];
  const float* Wfc = (const float*)d_in[4];
  const float* bfc = (const float*)d_in[5];
  float* out = (float*)d_out;
  hipLaunchKernelGGL(lstm_persist, dim3(256), dim3(NTH), 0, stream,
                     x, W, U, b, Wfc, bfc, out);
}

// Round 3
// 500.415 us; speedup vs baseline: 1.3089x; 1.2863x over previous
//
#include <hip/hip_runtime.h>

typedef _Float16 h8  __attribute__((ext_vector_type(8)));
typedef _Float16 hh4 __attribute__((ext_vector_type(4)));
typedef float    f4  __attribute__((ext_vector_type(4)));

#define TT 1024
#define FF 64
#define NTH 512
#define GRP 16
#define NGRP (TT / GRP)
#define K2 2.8853900817779268f   // 2/ln2

// swizzle on fp16 element index: byte ^= (row&7)<<4  ==  elem ^= (row&7)<<3
#define HSWZ(r, e) ((e) ^ (((r) & 7) << 3))

__device__ __forceinline__ float tanh0(float z) {
  float e = __builtin_amdgcn_exp2f(z * K2);
  return __builtin_fmaf(-2.0f, __builtin_amdgcn_rcpf(e + 1.0f), 1.0f);
}

#define MFMA __builtin_amdgcn_mfma_f32_16x16x32_f16

// One persistent block per 2 batch rows. 8 waves; wave wv owns hidden cols
// [wv*16,wv*16+16) of each gate. Batch row r lives at M-row 4r so its gate
// pre-activations land in lane-group r, reg 0 (C layout: row=4*(lane>>4)+reg).
// x@W is hoisted out of the recurrence: every GRP steps one bulk MFMA burst
// computes Zx (= x@W + bias) for the next GRP timesteps into LDS.
__global__ __launch_bounds__(NTH, 2) void lstm_persist(
    const float* __restrict__ X, const float* __restrict__ W,
    const float* __restrict__ U, const float* __restrict__ bias,
    const float* __restrict__ Wfc, const float* __restrict__ bfcp,
    float* __restrict__ out)
{
  const int tid = threadIdx.x;
  const int wv = tid >> 6, ln = tid & 63;
  const int l15 = ln & 15, lg = ln >> 4;
  const int row0 = blockIdx.x * 2;
  const int ncol = wv * 16 + l15;

  __shared__ __align__(16) _Float16 h_s[2][16 * 128];    // 8KB  (rows 0,4 live)
  __shared__ __align__(16) _Float16 x_s[32 * 64];        // 4KB  row m = 2*tt + r
  __shared__ __align__(16) _Float16 zx_s[32 * 128 * 4];  // 32KB [m][ncol][gate]
  __shared__ float red[8][2];

  // ---- persistent weight fragments (fp16, k-map k = 32f + 8lg + e, shared by A&B) ----
  h8 uf[4][4], wf4[4][2];
  f4 bias4[4];
#pragma unroll
  for (int g = 0; g < 4; ++g) {
    const int n = g * 128 + ncol;
#pragma unroll
    for (int f = 0; f < 4; ++f) {
      h8 v;
#pragma unroll
      for (int e = 0; e < 8; ++e) v[e] = (_Float16)U[(32 * f + 8 * lg + e) * 512 + n];
      uf[g][f] = v;
    }
#pragma unroll
    for (int f = 0; f < 2; ++f) {
      h8 v;
#pragma unroll
      for (int e = 0; e < 8; ++e) v[e] = (_Float16)W[(32 * f + 8 * lg + e) * 512 + n];
      wf4[g][f] = v;
    }
    const float bv = bias[n];
    f4 b4 = {bv, bv, bv, bv};
    bias4[g] = b4;
  }
  const float wfc = Wfc[ncol];

  // h-fragment offsets (elements, swizzled, one ds_read_b128 each)
  int hofs[4];
#pragma unroll
  for (int f = 0; f < 4; ++f) hofs[f] = HSWZ(l15, l15 * 128 + 32 * f + 8 * lg);
  // bulk x-fragment offsets: A rows m = mt*16 + l15
  int bxofs[2][2];
#pragma unroll
  for (int mt = 0; mt < 2; ++mt)
#pragma unroll
    for (int f = 0; f < 2; ++f)
      bxofs[mt][f] = HSWZ(l15, (mt * 16 + l15) * 64 + 32 * f + 8 * lg);

  const int zrbase = (lg & 1) * 512 + ncol * 4;  // per-step zx read (elem), m=2S+(lg&1)
  const int zwbase = lg * 2048 + ncol * 4;       // bulk zx write base (elem)
  const int hwofs  = HSWZ(4 * (lg & 1), 4 * (lg & 1) * 128 + ncol);  // used when lg<2

  // x staging map: thread -> (m = 2*tt + r, 4 consecutive k)
  const int sm = tid >> 4;
  const int sk = (tid & 15) * 4;
  const int sxofs = HSWZ(sm, sm * 64 + sk);
  const size_t xoff0 = (size_t)(row0 + (sm & 1)) * (TT * FF) + (size_t)(sm >> 1) * FF + sk;

  // zero h_s (rows other than 0,4 stay zero forever -> M=16 tile padding)
  {
    _Float16* p = &h_s[0][0];
    for (int i = tid; i < 2 * 16 * 128; i += NTH) p[i] = (_Float16)0.0f;
  }

  f4 xg = *(const f4*)(X + xoff0);   // group-0 x chunk in regs
  float cc = 0.f;
  const f4 zq = {0.f, 0.f, 0.f, 0.f};
  __syncthreads();

#define STEP(S, CUR, NXT) {                                                   \
    const _Float16* hb = &h_s[CUR][0];                                        \
    hh4 q4 = *(const hh4*)(&zx_s[zrbase + (S) * 1024]);                       \
    h8 ha0 = *(const h8*)(hb + hofs[0]);                                      \
    h8 ha1 = *(const h8*)(hb + hofs[1]);                                      \
    h8 ha2 = *(const h8*)(hb + hofs[2]);                                      \
    h8 ha3 = *(const h8*)(hb + hofs[3]);                                      \
    f4 a0 = MFMA(ha0, uf[0][0], zq, 0, 0, 0);                                 \
    f4 a1 = MFMA(ha0, uf[1][0], zq, 0, 0, 0);                                 \
    f4 a2 = MFMA(ha0, uf[2][0], zq, 0, 0, 0);                                 \
    f4 a3 = MFMA(ha0, uf[3][0], zq, 0, 0, 0);                                 \
    a0 = MFMA(ha1, uf[0][1], a0, 0, 0, 0);                                    \
    a1 = MFMA(ha1, uf[1][1], a1, 0, 0, 0);                                    \
    a2 = MFMA(ha1, uf[2][1], a2, 0, 0, 0);                                    \
    a3 = MFMA(ha1, uf[3][1], a3, 0, 0, 0);                                    \
    a0 = MFMA(ha2, uf[0][2], a0, 0, 0, 0);                                    \
    a1 = MFMA(ha2, uf[1][2], a1, 0, 0, 0);                                    \
    a2 = MFMA(ha2, uf[2][2], a2, 0, 0, 0);                                    \
    a3 = MFMA(ha2, uf[3][2], a3, 0, 0, 0);                                    \
    a0 = MFMA(ha3, uf[0][3], a0, 0, 0, 0);                                    \
    a1 = MFMA(ha3, uf[1][3], a1, 0, 0, 0);                                    \
    a2 = MFMA(ha3, uf[2][3], a2, 0, 0, 0);                                    \
    a3 = MFMA(ha3, uf[3][3], a3, 0, 0, 0);                                    \
    float zi = a0[0] + (float)q4[0];                                          \
    float zf = a1[0] + (float)q4[1];                                          \
    float zc = a2[0] + (float)q4[2];                                          \
    float zo = a3[0] + (float)q4[3];                                          \
    float ti = tanh0(zi), tf = tanh0(zf), tg = tanh0(zc), to = tanh0(zo);     \
    cc = __builtin_fmaf(tf, cc, ti * tg);                                     \
    float hv = to * tanh0(cc);                                                \
    if (lg < 2) h_s[NXT][hwofs] = (_Float16)hv;                               \
    __syncthreads();                                                          \
  }

#pragma unroll 1
  for (int grp = 0; grp < NGRP; ++grp) {
    // ---- stage this group's x chunk (regs -> LDS, fp16) ----
    {
      hh4 pk;
#pragma unroll
      for (int j = 0; j < 4; ++j) pk[j] = (_Float16)xg[j];
      *(hh4*)(&x_s[sxofs]) = pk;
    }
    __syncthreads();

    // ---- bulk: Zx[m][*] = x_chunk @ W + bias, m = 0..31 ----
    h8 xa00 = *(const h8*)(&x_s[bxofs[0][0]]);
    h8 xa01 = *(const h8*)(&x_s[bxofs[0][1]]);
    h8 xa10 = *(const h8*)(&x_s[bxofs[1][0]]);
    h8 xa11 = *(const h8*)(&x_s[bxofs[1][1]]);
    f4 b00 = MFMA(xa00, wf4[0][0], bias4[0], 0, 0, 0);
    f4 b01 = MFMA(xa00, wf4[1][0], bias4[1], 0, 0, 0);
    f4 b02 = MFMA(xa00, wf4[2][0], bias4[2], 0, 0, 0);
    f4 b03 = MFMA(xa00, wf4[3][0], bias4[3], 0, 0, 0);
    b00 = MFMA(xa01, wf4[0][1], b00, 0, 0, 0);
    b01 = MFMA(xa01, wf4[1][1], b01, 0, 0, 0);
    b02 = MFMA(xa01, wf4[2][1], b02, 0, 0, 0);
    b03 = MFMA(xa01, wf4[3][1], b03, 0, 0, 0);
    f4 b10 = MFMA(xa10, wf4[0][0], bias4[0], 0, 0, 0);
    f4 b11 = MFMA(xa10, wf4[1][0], bias4[1], 0, 0, 0);
    f4 b12 = MFMA(xa10, wf4[2][0], bias4[2], 0, 0, 0);
    f4 b13 = MFMA(xa10, wf4[3][0], bias4[3], 0, 0, 0);
    b10 = MFMA(xa11, wf4[0][1], b10, 0, 0, 0);
    b11 = MFMA(xa11, wf4[1][1], b11, 0, 0, 0);
    b12 = MFMA(xa11, wf4[2][1], b12, 0, 0, 0);
    b13 = MFMA(xa11, wf4[3][1], b13, 0, 0, 0);
    // scatter to zx_s: elem = (mt*16 + 4lg + j)*512 + ncol*4 + g
#pragma unroll
    for (int j = 0; j < 4; ++j) {
      zx_s[zwbase + (0 * 16 + j) * 512 + 0] = (_Float16)b00[j];
      zx_s[zwbase + (0 * 16 + j) * 512 + 1] = (_Float16)b01[j];
      zx_s[zwbase + (0 * 16 + j) * 512 + 2] = (_Float16)b02[j];
      zx_s[zwbase + (0 * 16 + j) * 512 + 3] = (_Float16)b03[j];
      zx_s[zwbase + (1 * 16 + j) * 512 + 0] = (_Float16)b10[j];
      zx_s[zwbase + (1 * 16 + j) * 512 + 1] = (_Float16)b11[j];
      zx_s[zwbase + (1 * 16 + j) * 512 + 2] = (_Float16)b12[j];
      zx_s[zwbase + (1 * 16 + j) * 512 + 3] = (_Float16)b13[j];
    }
    // prefetch next group's x into regs (covered by the 16 steps below)
    {
      const int t0n = (grp + 1 < NGRP ? grp + 1 : grp) * GRP;
      xg = *(const f4*)(X + xoff0 + (size_t)t0n * FF);
    }
    __syncthreads();

    // ---- 16 recurrent steps ----
#pragma unroll
    for (int s2 = 0; s2 < 8; ++s2) {
      STEP(2 * s2,     0, 1)
      STEP(2 * s2 + 1, 1, 0)
    }
  }
#undef STEP

  // ---- epilogue: y[r] = h_last[r,:] @ Wfc + bfc  (h_last in buffer 0, rows 0/4) ----
  float hw0 = (float)h_s[0][HSWZ(0, ncol)];
  float hw1 = (float)h_s[0][HSWZ(4, 4 * 128 + ncol)];
  float p0 = hw0 * wfc;
  float p1 = hw1 * wfc;
#pragma unroll
  for (int m = 1; m < 16; m <<= 1) {
    p0 += __shfl_xor(p0, m, 16);
    p1 += __shfl_xor(p1, m, 16);
  }
  if (ln == 0) { red[wv][0] = p0; red[wv][1] = p1; }
  __syncthreads();
  if (tid < 2) {
    float y = bfcp[0];
#pragma unroll
    for (int w2 = 0; w2 < 8; ++w2) y += red[w2][tid];
    out[row0 + tid] = y;
  }
}

extern "C" void kernel_launch(void* const* d_in, const int* in_sizes, int n_in,
                              void* d_out, int out_size, void* d_ws, size_t ws_size,
                              hipStream_t stream) {
  const float* x   = (const float*)d_in[0];
  const float* W   = (const float*)d_in[1];
  const float* U   = (const float*)d_in[2];
  const float* b   = (const float*)d_in[3];
  const float* Wfc = (const float*)d_in[4];
  const float* bfc = (const float*)d_in[5];
  float* out = (float*)d_out;
  hipLaunchKernelGGL(lstm_persist, dim3(256), dim3(NTH), 0, stream,
                     x, W, U, b, Wfc, bfc, out);
}

// Round 4
// 482.537 us; speedup vs baseline: 1.3574x; 1.0371x over previous
//
#include <hip/hip_runtime.h>

typedef _Float16 h8  __attribute__((ext_vector_type(8)));
typedef _Float16 hh4 __attribute__((ext_vector_type(4)));
typedef float    f4  __attribute__((ext_vector_type(4)));

#define TT 1024
#define FF 64
#define NTH 512
#define GRP 16
#define NGRP (TT / GRP)
#define K2 2.8853900817779268f   // 2/ln2

// swizzle for x_s only: elem ^= (row&7)<<3
#define HSWZ(r, e) ((e) ^ (((r) & 7) << 3))

__device__ __forceinline__ float tanh0(float z) {
  float e = __builtin_amdgcn_exp2f(z * K2);
  return __builtin_fmaf(-2.0f, __builtin_amdgcn_rcpf(e + 1.0f), 1.0f);
}

#define MFMA __builtin_amdgcn_mfma_f32_16x16x32_f16

// One persistent block per 2 batch rows. 8 waves; wave wv owns hidden cols
// [wv*16,wv*16+16) of each gate. Batch row r lives at M-row 4r (C layout:
// row = 4*(lane>>4)+reg -> row r lands in lane-group r, reg 0).
// h is stored COMPACT in LDS (h_s[buf][2][128], 1KB): A-fragment reads are
// real only for lanes l15==0 (row 0) / l15==4 (row 1); all other lanes read
// offset 0 -> same-address broadcast, near-zero LDS bank traffic.
// x@W is hoisted: every GRP steps one bulk MFMA burst fills Zx in LDS.
__global__ __launch_bounds__(NTH, 2) void lstm_persist(
    const float* __restrict__ X, const float* __restrict__ W,
    const float* __restrict__ U, const float* __restrict__ bias,
    const float* __restrict__ Wfc, const float* __restrict__ bfcp,
    float* __restrict__ out)
{
  const int tid = threadIdx.x;
  const int wv = tid >> 6, ln = tid & 63;
  const int l15 = ln & 15, lg = ln >> 4;
  const int row0 = blockIdx.x * 2;
  const int ncol = wv * 16 + l15;

  __shared__ __align__(16) _Float16 h_s[2][2 * 128];     // 1KB compact [buf][row][col]
  __shared__ __align__(16) _Float16 x_s[32 * 64];        // 4KB row m = 2*tt + r (swizzled)
  __shared__ __align__(16) _Float16 zx_s[32 * 512];      // 32KB [m][ncol*4+gate]
  __shared__ float red[8][2];

  // ---- persistent weight fragments (fp16, k-map k = 32f + 8lg + e, shared by A&B) ----
  h8 uf[4][4], wf4[4][2];
  f4 bias4[4];
#pragma unroll
  for (int g = 0; g < 4; ++g) {
    const int n = g * 128 + ncol;
#pragma unroll
    for (int f = 0; f < 4; ++f) {
      h8 v;
#pragma unroll
      for (int e = 0; e < 8; ++e) v[e] = (_Float16)U[(32 * f + 8 * lg + e) * 512 + n];
      uf[g][f] = v;
    }
#pragma unroll
    for (int f = 0; f < 2; ++f) {
      h8 v;
#pragma unroll
      for (int e = 0; e < 8; ++e) v[e] = (_Float16)W[(32 * f + 8 * lg + e) * 512 + n];
      wf4[g][f] = v;
    }
    const float bv = bias[n];
    f4 b4 = {bv, bv, bv, bv};
    bias4[g] = b4;
  }
  const float wfc = Wfc[ncol];

  // h-fragment offsets into compact h_s[buf]: real for l15==0 (row0) / l15==4 (row1),
  // everyone else points at 0 (same-address broadcast, no bank cost).
  int hofs[4];
#pragma unroll
  for (int f = 0; f < 4; ++f) {
    const int base = 32 * f + 8 * lg;
    hofs[f] = (l15 == 0) ? base : (l15 == 4) ? 128 + base : 0;
  }
  // bulk x-fragment offsets (x_s swizzled): A rows m = mt*16 + l15
  int bxofs[2][2];
#pragma unroll
  for (int mt = 0; mt < 2; ++mt)
#pragma unroll
    for (int f = 0; f < 2; ++f)
      bxofs[mt][f] = HSWZ(l15, (mt * 16 + l15) * 64 + 32 * f + 8 * lg);

  // zx per-step read: lane (lg in {0,1}, l15) needs m=2S+lg, 4 gates at ncol*4.
  // lg>=2 lanes -> offset 0 (broadcast).
  const int zofs  = (lg < 2) ? (lg * 512 + ncol * 4) : 0;
  const int zwofs = ncol * 4;                 // bulk scatter base (elem, + m*512)
  const int hwofs = (lg & 1) * 128 + ncol;    // h write (lg<2 only)

  // x staging map: thread -> (m = 2*tt + r, 4 consecutive k)
  const int sm = tid >> 4;
  const int sk = (tid & 15) * 4;
  const int sxofs = HSWZ(sm, sm * 64 + sk);
  const size_t xoff0 = (size_t)(row0 + (sm & 1)) * (TT * FF) + (size_t)(sm >> 1) * FF + sk;

  // zero compact h (both buffers; 512 elems, 1 per thread)
  ((_Float16*)h_s)[tid] = (_Float16)0.0f;

  f4 xg = *(const f4*)(X + xoff0);   // group-0 x chunk in regs
  float cc = 0.f;
  const f4 zq = {0.f, 0.f, 0.f, 0.f};
  __syncthreads();

#define STEP(S, CUR, NXT) {                                                   \
    const _Float16* hb = &h_s[CUR][0];                                        \
    h8 ha0 = *(const h8*)(hb + hofs[0]);                                      \
    h8 ha1 = *(const h8*)(hb + hofs[1]);                                      \
    h8 ha2 = *(const h8*)(hb + hofs[2]);                                      \
    h8 ha3 = *(const h8*)(hb + hofs[3]);                                      \
    hh4 q4 = *(const hh4*)(&zx_s[zofs + (S) * 1024]);                         \
    f4 a0 = MFMA(ha0, uf[0][0], zq, 0, 0, 0);                                 \
    f4 a1 = MFMA(ha0, uf[1][0], zq, 0, 0, 0);                                 \
    f4 a2 = MFMA(ha0, uf[2][0], zq, 0, 0, 0);                                 \
    f4 a3 = MFMA(ha0, uf[3][0], zq, 0, 0, 0);                                 \
    a0 = MFMA(ha1, uf[0][1], a0, 0, 0, 0);                                    \
    a1 = MFMA(ha1, uf[1][1], a1, 0, 0, 0);                                    \
    a2 = MFMA(ha1, uf[2][1], a2, 0, 0, 0);                                    \
    a3 = MFMA(ha1, uf[3][1], a3, 0, 0, 0);                                    \
    a0 = MFMA(ha2, uf[0][2], a0, 0, 0, 0);                                    \
    a1 = MFMA(ha2, uf[1][2], a1, 0, 0, 0);                                    \
    a2 = MFMA(ha2, uf[2][2], a2, 0, 0, 0);                                    \
    a3 = MFMA(ha2, uf[3][2], a3, 0, 0, 0);                                    \
    a0 = MFMA(ha3, uf[0][3], a0, 0, 0, 0);                                    \
    a1 = MFMA(ha3, uf[1][3], a1, 0, 0, 0);                                    \
    a2 = MFMA(ha3, uf[2][3], a2, 0, 0, 0);                                    \
    a3 = MFMA(ha3, uf[3][3], a3, 0, 0, 0);                                    \
    float zi = a0[0] + (float)q4[0];                                          \
    float zf = a1[0] + (float)q4[1];                                          \
    float zc = a2[0] + (float)q4[2];                                          \
    float zo = a3[0] + (float)q4[3];                                          \
    float ti = tanh0(zi), tf = tanh0(zf), tg = tanh0(zc), to = tanh0(zo);     \
    cc = __builtin_fmaf(tf, cc, ti * tg);                                     \
    float hv = to * tanh0(cc);                                                \
    if (lg < 2) h_s[NXT][hwofs] = (_Float16)hv;                               \
    __syncthreads();                                                          \
  }

#pragma unroll 1
  for (int grp = 0; grp < NGRP; ++grp) {
    // ---- stage this group's x chunk (regs -> LDS, fp16) ----
    {
      hh4 pk;
#pragma unroll
      for (int j = 0; j < 4; ++j) pk[j] = (_Float16)xg[j];
      *(hh4*)(&x_s[sxofs]) = pk;
    }
    __syncthreads();

    // ---- bulk: Zx[m][*] = x_chunk @ W + bias, m = 0..31 ----
    h8 xa00 = *(const h8*)(&x_s[bxofs[0][0]]);
    h8 xa01 = *(const h8*)(&x_s[bxofs[0][1]]);
    h8 xa10 = *(const h8*)(&x_s[bxofs[1][0]]);
    h8 xa11 = *(const h8*)(&x_s[bxofs[1][1]]);
    f4 b00 = MFMA(xa00, wf4[0][0], bias4[0], 0, 0, 0);
    f4 b01 = MFMA(xa00, wf4[1][0], bias4[1], 0, 0, 0);
    f4 b02 = MFMA(xa00, wf4[2][0], bias4[2], 0, 0, 0);
    f4 b03 = MFMA(xa00, wf4[3][0], bias4[3], 0, 0, 0);
    b00 = MFMA(xa01, wf4[0][1], b00, 0, 0, 0);
    b01 = MFMA(xa01, wf4[1][1], b01, 0, 0, 0);
    b02 = MFMA(xa01, wf4[2][1], b02, 0, 0, 0);
    b03 = MFMA(xa01, wf4[3][1], b03, 0, 0, 0);
    f4 b10 = MFMA(xa10, wf4[0][0], bias4[0], 0, 0, 0);
    f4 b11 = MFMA(xa10, wf4[1][0], bias4[1], 0, 0, 0);
    f4 b12 = MFMA(xa10, wf4[2][0], bias4[2], 0, 0, 0);
    f4 b13 = MFMA(xa10, wf4[3][0], bias4[3], 0, 0, 0);
    b10 = MFMA(xa11, wf4[0][1], b10, 0, 0, 0);
    b11 = MFMA(xa11, wf4[1][1], b11, 0, 0, 0);
    b12 = MFMA(xa11, wf4[2][1], b12, 0, 0, 0);
    b13 = MFMA(xa11, wf4[3][1], b13, 0, 0, 0);
    // packed scatter: m = mt*16 + 4lg + j, 4 gates -> one ds_write_b64
#pragma unroll
    for (int j = 0; j < 4; ++j) {
      hh4 p0; p0[0] = (_Float16)b00[j]; p0[1] = (_Float16)b01[j];
              p0[2] = (_Float16)b02[j]; p0[3] = (_Float16)b03[j];
      *(hh4*)(&zx_s[(0 * 16 + 4 * lg + j) * 512 + zwofs]) = p0;
      hh4 p1; p1[0] = (_Float16)b10[j]; p1[1] = (_Float16)b11[j];
              p1[2] = (_Float16)b12[j]; p1[3] = (_Float16)b13[j];
      *(hh4*)(&zx_s[(1 * 16 + 4 * lg + j) * 512 + zwofs]) = p1;
    }
    // prefetch next group's x into regs (covered by the 16 steps below)
    {
      const int t0n = (grp + 1 < NGRP ? grp + 1 : grp) * GRP;
      xg = *(const f4*)(X + xoff0 + (size_t)t0n * FF);
    }
    __syncthreads();

    // ---- 16 recurrent steps ----
#pragma unroll
    for (int s2 = 0; s2 < 8; ++s2) {
      STEP(2 * s2,     0, 1)
      STEP(2 * s2 + 1, 1, 0)
    }
  }
#undef STEP

  // ---- epilogue: y[r] = h_last[r,:] @ Wfc + bfc  (h_last in buffer 0) ----
  float hw0 = (float)h_s[0][ncol];
  float hw1 = (float)h_s[0][128 + ncol];
  float p0 = hw0 * wfc;
  float p1 = hw1 * wfc;
#pragma unroll
  for (int m = 1; m < 16; m <<= 1) {
    p0 += __shfl_xor(p0, m, 16);
    p1 += __shfl_xor(p1, m, 16);
  }
  if (ln == 0) { red[wv][0] = p0; red[wv][1] = p1; }
  __syncthreads();
  if (tid < 2) {
    float y = bfcp[0];
#pragma unroll
    for (int w2 = 0; w2 < 8; ++w2) y += red[w2][tid];
    out[row0 + tid] = y;
  }
}

extern "C" void kernel_launch(void* const* d_in, const int* in_sizes, int n_in,
                              void* d_out, int out_size, void* d_ws, size_t ws_size,
                              hipStream_t stream) {
  const float* x   = (const float*)d_in[0];
  const float* W   = (const float*)d_in[1];
  const float* U   = (const float*)d_in[2];
  const float* b   = (const float*)d_in[3];
  const float* Wfc = (const float*)d_in[4];
  const float* bfc = (const float*)d_in[5];
  float* out = (float*)d_out;
  hipLaunchKernelGGL(lstm_persist, dim3(256), dim3(NTH), 0, stream,
                     x, W, U, b, Wfc, bfc, out);
}

// Round 5
// 462.349 us; speedup vs baseline: 1.4167x; 1.0437x over previous
//
#include <hip/hip_runtime.h>

typedef _Float16 h8  __attribute__((ext_vector_type(8)));
typedef _Float16 hh4 __attribute__((ext_vector_type(4)));
typedef float    f4  __attribute__((ext_vector_type(4)));

#define TT 1024
#define FF 64
#define NTH 512
#define GRP 16
#define NGRP (TT / GRP)
#define K2 2.8853900817779268f   // 2/ln2

// swizzle for x_s only: elem ^= (row&7)<<3
#define HSWZ(r, e) ((e) ^ (((r) & 7) << 3))

__device__ __forceinline__ float tanh0(float z) {
  float e = __builtin_amdgcn_exp2f(z * K2);
  return __builtin_fmaf(-2.0f, __builtin_amdgcn_rcpf(e + 1.0f), 1.0f);
}

#define MFMA __builtin_amdgcn_mfma_f32_16x16x32_f16
#define FENCE() __builtin_amdgcn_sched_barrier(0)

// One persistent block per 2 batch rows. 8 waves; wave wv owns hidden cols
// [wv*16,wv*16+16) of each gate. Batch row r lives at M-row 4r (C layout:
// row = 4*(lane>>4)+reg -> row r lands in lane-group r, reg 0).
// h compact in LDS; non-owner lanes read offset 0 (broadcast) / write scratch row.
// x@W hoisted per GRP steps (bulk MFMA into zx_s, fp16).
// Step schedule is g-major: [4 MFMA chain][tanh of that gate] x4, with
// sched_barrier(0) pins so gate tanh VALU overlaps the next gate's MFMAs.
__global__ __launch_bounds__(NTH, 2) void lstm_persist(
    const float* __restrict__ X, const float* __restrict__ W,
    const float* __restrict__ U, const float* __restrict__ bias,
    const float* __restrict__ Wfc, const float* __restrict__ bfcp,
    float* __restrict__ out)
{
  const int tid = threadIdx.x;
  const int wv = tid >> 6, ln = tid & 63;
  const int l15 = ln & 15, lg = ln >> 4;
  const int row0 = blockIdx.x * 2;
  const int ncol = wv * 16 + l15;

  __shared__ __align__(16) _Float16 h_s[2][384];         // rows 0,1 live; row2 = scratch
  __shared__ __align__(16) _Float16 x_s[32 * 64];        // 4KB row m = 2*tt + r (swizzled)
  __shared__ __align__(16) _Float16 zx_s[32 * 512];      // 32KB [m][ncol*4+gate]
  __shared__ float red[8][2];

  // ---- persistent weight fragments (fp16, k-map k = 32f + 8lg + e, shared by A&B) ----
  h8 uf[4][4], wf4[4][2];
  f4 bias4[4];
#pragma unroll
  for (int g = 0; g < 4; ++g) {
    const int n = g * 128 + ncol;
#pragma unroll
    for (int f = 0; f < 4; ++f) {
      h8 v;
#pragma unroll
      for (int e = 0; e < 8; ++e) v[e] = (_Float16)U[(32 * f + 8 * lg + e) * 512 + n];
      uf[g][f] = v;
    }
#pragma unroll
    for (int f = 0; f < 2; ++f) {
      h8 v;
#pragma unroll
      for (int e = 0; e < 8; ++e) v[e] = (_Float16)W[(32 * f + 8 * lg + e) * 512 + n];
      wf4[g][f] = v;
    }
    const float bv = bias[n];
    f4 b4 = {bv, bv, bv, bv};
    bias4[g] = b4;
  }
  const float wfc = Wfc[ncol];

  // h-fragment offsets into compact h_s[buf]: real for l15==0 (row0) / l15==4 (row1),
  // everyone else points at 0 (same-address broadcast).
  int hofs[4];
#pragma unroll
  for (int f = 0; f < 4; ++f) {
    const int base = 32 * f + 8 * lg;
    hofs[f] = (l15 == 0) ? base : (l15 == 4) ? 128 + base : 0;
  }
  // bulk x-fragment offsets (x_s swizzled): A rows m = mt*16 + l15
  int bxofs[2][2];
#pragma unroll
  for (int mt = 0; mt < 2; ++mt)
#pragma unroll
    for (int f = 0; f < 2; ++f)
      bxofs[mt][f] = HSWZ(l15, (mt * 16 + l15) * 64 + 32 * f + 8 * lg);

  // zx per-step read: lane (lg in {0,1}, l15) needs m=2S+lg at ncol*4; lg>=2 -> broadcast 0
  const int zofs  = (lg < 2) ? (lg * 512 + ncol * 4) : 0;
  const int zwofs = ncol * 4;                                  // bulk scatter base
  const int hwofs = (lg < 2) ? (lg * 128 + ncol) : (256 + ncol);  // scratch row for lg>=2

  // x staging map: thread -> (m = 2*tt + r, 4 consecutive k)
  const int sm = tid >> 4;
  const int sk = (tid & 15) * 4;
  const int sxofs = HSWZ(sm, sm * 64 + sk);
  const size_t xoff0 = (size_t)(row0 + (sm & 1)) * (TT * FF) + (size_t)(sm >> 1) * FF + sk;

  // zero compact h (both buffers, incl. scratch rows)
  for (int i = tid; i < 2 * 384; i += NTH) ((_Float16*)h_s)[i] = (_Float16)0.0f;

  f4 xg = *(const f4*)(X + xoff0);   // group-0 x chunk in regs
  float cc = 0.f;
  const f4 zq = {0.f, 0.f, 0.f, 0.f};
  hh4 q4cur;
  __syncthreads();

#define STEP(S, CUR, NXT, DOPF) {                                             \
    const _Float16* hb = &h_s[CUR][0];                                        \
    h8 ha0 = *(const h8*)(hb + hofs[0]);                                      \
    h8 ha1 = *(const h8*)(hb + hofs[1]);                                      \
    h8 ha2 = *(const h8*)(hb + hofs[2]);                                      \
    h8 ha3 = *(const h8*)(hb + hofs[3]);                                      \
    f4 a0 = MFMA(ha0, uf[0][0], zq, 0, 0, 0);                                 \
    a0 = MFMA(ha1, uf[0][1], a0, 0, 0, 0);                                    \
    a0 = MFMA(ha2, uf[0][2], a0, 0, 0, 0);                                    \
    a0 = MFMA(ha3, uf[0][3], a0, 0, 0, 0);                                    \
    float ti = tanh0(a0[0] + (float)q4cur[0]);                                \
    FENCE();                                                                  \
    f4 a1 = MFMA(ha0, uf[1][0], zq, 0, 0, 0);                                 \
    a1 = MFMA(ha1, uf[1][1], a1, 0, 0, 0);                                    \
    a1 = MFMA(ha2, uf[1][2], a1, 0, 0, 0);                                    \
    a1 = MFMA(ha3, uf[1][3], a1, 0, 0, 0);                                    \
    float tf = tanh0(a1[0] + (float)q4cur[1]);                                \
    FENCE();                                                                  \
    f4 a2 = MFMA(ha0, uf[2][0], zq, 0, 0, 0);                                 \
    a2 = MFMA(ha1, uf[2][1], a2, 0, 0, 0);                                    \
    a2 = MFMA(ha2, uf[2][2], a2, 0, 0, 0);                                    \
    a2 = MFMA(ha3, uf[2][3], a2, 0, 0, 0);                                    \
    float tg = tanh0(a2[0] + (float)q4cur[2]);                                \
    cc = __builtin_fmaf(tf, cc, ti * tg);                                     \
    FENCE();                                                                  \
    f4 a3 = MFMA(ha0, uf[3][0], zq, 0, 0, 0);                                 \
    a3 = MFMA(ha1, uf[3][1], a3, 0, 0, 0);                                    \
    a3 = MFMA(ha2, uf[3][2], a3, 0, 0, 0);                                    \
    a3 = MFMA(ha3, uf[3][3], a3, 0, 0, 0);                                    \
    float to = tanh0(a3[0] + (float)q4cur[3]);                                \
    float hv = to * tanh0(cc);                                                \
    h_s[NXT][hwofs] = (_Float16)hv;                                           \
    if (DOPF) q4cur = *(const hh4*)(&zx_s[zofs + ((S) + 1) * 1024]);          \
    __syncthreads();                                                          \
  }

#pragma unroll 1
  for (int grp = 0; grp < NGRP; ++grp) {
    // ---- stage this group's x chunk (regs -> LDS, fp16) ----
    {
      hh4 pk;
#pragma unroll
      for (int j = 0; j < 4; ++j) pk[j] = (_Float16)xg[j];
      *(hh4*)(&x_s[sxofs]) = pk;
    }
    __syncthreads();

    // ---- bulk: Zx[m][*] = x_chunk @ W + bias, m = 0..31 ----
    h8 xa00 = *(const h8*)(&x_s[bxofs[0][0]]);
    h8 xa01 = *(const h8*)(&x_s[bxofs[0][1]]);
    h8 xa10 = *(const h8*)(&x_s[bxofs[1][0]]);
    h8 xa11 = *(const h8*)(&x_s[bxofs[1][1]]);
    f4 b00 = MFMA(xa00, wf4[0][0], bias4[0], 0, 0, 0);
    f4 b01 = MFMA(xa00, wf4[1][0], bias4[1], 0, 0, 0);
    f4 b02 = MFMA(xa00, wf4[2][0], bias4[2], 0, 0, 0);
    f4 b03 = MFMA(xa00, wf4[3][0], bias4[3], 0, 0, 0);
    b00 = MFMA(xa01, wf4[0][1], b00, 0, 0, 0);
    b01 = MFMA(xa01, wf4[1][1], b01, 0, 0, 0);
    b02 = MFMA(xa01, wf4[2][1], b02, 0, 0, 0);
    b03 = MFMA(xa01, wf4[3][1], b03, 0, 0, 0);
    f4 b10 = MFMA(xa10, wf4[0][0], bias4[0], 0, 0, 0);
    f4 b11 = MFMA(xa10, wf4[1][0], bias4[1], 0, 0, 0);
    f4 b12 = MFMA(xa10, wf4[2][0], bias4[2], 0, 0, 0);
    f4 b13 = MFMA(xa10, wf4[3][0], bias4[3], 0, 0, 0);
    b10 = MFMA(xa11, wf4[0][1], b10, 0, 0, 0);
    b11 = MFMA(xa11, wf4[1][1], b11, 0, 0, 0);
    b12 = MFMA(xa11, wf4[2][1], b12, 0, 0, 0);
    b13 = MFMA(xa11, wf4[3][1], b13, 0, 0, 0);
    // packed scatter: m = mt*16 + 4lg + j, 4 gates -> one ds_write_b64
#pragma unroll
    for (int j = 0; j < 4; ++j) {
      hh4 p0; p0[0] = (_Float16)b00[j]; p0[1] = (_Float16)b01[j];
              p0[2] = (_Float16)b02[j]; p0[3] = (_Float16)b03[j];
      *(hh4*)(&zx_s[(0 * 16 + 4 * lg + j) * 512 + zwofs]) = p0;
      hh4 p1; p1[0] = (_Float16)b10[j]; p1[1] = (_Float16)b11[j];
              p1[2] = (_Float16)b12[j]; p1[3] = (_Float16)b13[j];
      *(hh4*)(&zx_s[(1 * 16 + 4 * lg + j) * 512 + zwofs]) = p1;
    }
    // prefetch next group's x into regs (covered by the 16 steps below)
    {
      const int t0n = (grp + 1 < NGRP ? grp + 1 : grp) * GRP;
      xg = *(const f4*)(X + xoff0 + (size_t)t0n * FF);
    }
    __syncthreads();
    q4cur = *(const hh4*)(&zx_s[zofs]);   // step-0 zx

    // ---- 16 recurrent steps ----
#pragma unroll
    for (int s2 = 0; s2 < 8; ++s2) {
      STEP(2 * s2,     0, 1, 1)
      STEP(2 * s2 + 1, 1, 0, (2 * s2 + 1) != (GRP - 1))
    }
  }
#undef STEP

  // ---- epilogue: y[r] = h_last[r,:] @ Wfc + bfc  (h_last in buffer 0) ----
  float hw0 = (float)h_s[0][ncol];
  float hw1 = (float)h_s[0][128 + ncol];
  float p0 = hw0 * wfc;
  float p1 = hw1 * wfc;
#pragma unroll
  for (int m = 1; m < 16; m <<= 1) {
    p0 += __shfl_xor(p0, m, 16);
    p1 += __shfl_xor(p1, m, 16);
  }
  if (ln == 0) { red[wv][0] = p0; red[wv][1] = p1; }
  __syncthreads();
  if (tid < 2) {
    float y = bfcp[0];
#pragma unroll
    for (int w2 = 0; w2 < 8; ++w2) y += red[w2][tid];
    out[row0 + tid] = y;
  }
}

extern "C" void kernel_launch(void* const* d_in, const int* in_sizes, int n_in,
                              void* d_out, int out_size, void* d_ws, size_t ws_size,
                              hipStream_t stream) {
  const float* x   = (const float*)d_in[0];
  const float* W   = (const float*)d_in[1];
  const float* U   = (const float*)d_in[2];
  const float* b   = (const float*)d_in[3];
  const float* Wfc = (const float*)d_in[4];
  const float* bfc = (const float*)d_in[5];
  float* out = (float*)d_out;
  hipLaunchKernelGGL(lstm_persist, dim3(256), dim3(NTH), 0, stream,
                     x, W, U, b, Wfc, bfc, out);
}